// Round 1
// 211.270 us; speedup vs baseline: 1.0716x; 1.0716x over previous
//
#include <hip/hip_runtime.h>
#include <hip/hip_bf16.h>

typedef __attribute__((ext_vector_type(8))) __bf16 bf16x8;
typedef __attribute__((ext_vector_type(8))) short  s16x8;
typedef __attribute__((ext_vector_type(4))) short  s16x4;
typedef __attribute__((ext_vector_type(4))) float  f32x4;

#define HW2 1024   // h*w
#define CDIM 512   // channels

static __device__ __forceinline__ unsigned short f2b(float f) {
  __hip_bfloat16 h = __float2bfloat16(f);
  return __builtin_bit_cast(unsigned short, h);
}

static __device__ __forceinline__ f32x4 mfma16(s16x8 a, s16x8 b, f32x4 c) {
  return __builtin_amdgcn_mfma_f32_16x16x32_bf16(
      __builtin_bit_cast(bf16x8, a), __builtin_bit_cast(bf16x8, b), c, 0, 0, 0);
}

// ---------------- fused prep ----------------
// blocks [0,16): Wt*[c][k] = w_qkv[k][3c+s] (q pre-scaled by 1/8)
// blocks [16,1040): WhtT[c][k] = w_ht[k][c]
// blocks [1040,2064): pe[i] = table[idx[i]]  (output #2; NOT consumed by k_attn anymore)
__global__ __launch_bounds__(256) void k_prep(
    const float* __restrict__ w_qkv, const float* __restrict__ w_ht,
    const float* __restrict__ table, const int* __restrict__ idx,
    unsigned short* __restrict__ Wtq, unsigned short* __restrict__ Wtk,
    unsigned short* __restrict__ Wtv, unsigned short* __restrict__ WhtT,
    float* __restrict__ pe) {
  int blk = blockIdx.x;
  if (blk < 16) {
    int i = blk * 256 + threadIdx.x;           // 4096
    int c = i >> 6, k = i & 63;
    const float* src = w_qkv + k * 192 + 3 * c;
    Wtq[i] = f2b(src[0] * 0.125f);
    Wtk[i] = f2b(src[1]);
    Wtv[i] = f2b(src[2]);
  } else if (blk < 1040) {
    int i = (blk - 16) * 256 + threadIdx.x;    // 262144
    int c = i >> 9, k = i & 511;
    WhtT[i] = f2b(w_ht[k * 512 + c]);
  } else {
    int i = (blk - 1040) * 256 + threadIdx.x;  // 262144 threads x 4
    #pragma unroll
    for (int j = 0; j < 4; ++j) {
      int p = i + j * 262144;
      pe[p] = table[idx[p]];
    }
  }
}

// ---------------- QKV projection ----------------
// Per wg: one bm, 64 pixels. 4 waves x 16 rows. K=64, N=192 (12 col-tiles).
// Epilogue: LDS transpose -> fully coalesced b128 stores; V written directly
// in transposed [dh][p] layout (kills the separate transpose kernel).
__global__ __launch_bounds__(256) void k_qkv(const float* __restrict__ x,
    const float* __restrict__ b_qkv,
    const unsigned short* __restrict__ Wtq, const unsigned short* __restrict__ Wtk,
    const unsigned short* __restrict__ Wtv,
    unsigned short* __restrict__ Qb, unsigned short* __restrict__ Kb,
    unsigned short* __restrict__ Vt) {
  int bm = blockIdx.x >> 4;
  int pt = blockIdx.x & 15;
  int wid = threadIdx.x >> 6, lane = threadIdx.x & 63;
  int l15 = lane & 15, lg = lane >> 4;
  int b = bm >> 3, m = bm & 7;
  int pbase = pt * 64 + wid * 16;

  // Q tile at cols [0,64), K at [64,128), V^T at [128,192). Stride 200 elems
  // (=100 dwords, 100%32=4) spreads banks for the b128 read phase.
  __shared__ unsigned short T[64][200];

  // A-frags from x (f32 -> bf16)
  int pA = pbase + l15;
  const float* xp = x + (size_t)(b * HW2 + pA) * CDIM + m * 64 + lg * 8;
  f32x4 xv0 = *(const f32x4*)(xp);
  f32x4 xv1 = *(const f32x4*)(xp + 4);
  f32x4 xv2 = *(const f32x4*)(xp + 32);
  f32x4 xv3 = *(const f32x4*)(xp + 36);
  s16x8 a0, a1;
  #pragma unroll
  for (int j = 0; j < 4; ++j) {
    a0[j]     = (short)f2b(xv0[j]);
    a0[4 + j] = (short)f2b(xv1[j]);
    a1[j]     = (short)f2b(xv2[j]);
    a1[4 + j] = (short)f2b(xv3[j]);
  }

  f32x4 acc[12];
  #pragma unroll
  for (int ct = 0; ct < 12; ++ct) acc[ct] = (f32x4){0.f, 0.f, 0.f, 0.f};

  #pragma unroll
  for (int ct = 0; ct < 12; ++ct) {
    const unsigned short* W = (ct < 4) ? Wtq : (ct < 8 ? Wtk : Wtv);
    int c = (ct & 3) * 16 + l15;
    const unsigned short* wp = W + c * 64 + lg * 8;
    s16x8 b0 = *(const s16x8*)(wp);
    s16x8 b1 = *(const s16x8*)(wp + 32);
    acc[ct] = mfma16(a0, b0, acc[ct]);
    acc[ct] = mfma16(a1, b1, acc[ct]);
  }

  // accumulators -> LDS (bias applied, bf16)
  int lrow = wid * 16 + lg * 4;
  #pragma unroll
  for (int ct = 0; ct < 12; ++ct) {
    int s = ct >> 2;
    int c = (ct & 3) * 16 + l15;
    float bias = b_qkv[3 * c + s];
    if (s == 0) bias *= 0.125f;
    #pragma unroll
    for (int i = 0; i < 4; ++i) {
      unsigned short hv = f2b(acc[ct][i] + bias);
      if (s == 0)      T[lrow + i][c] = hv;
      else if (s == 1) T[lrow + i][64 + c] = hv;
      else             T[c][128 + lrow + i] = hv;   // V transposed: row=dh, col=p
    }
  }
  __syncthreads();

  // coalesced store phase: thread t -> row r = t>>2, 32B chunk cp = t&3
  int t = threadIdx.x;
  int r = t >> 2, cp = t & 3;
  size_t prow = (size_t)(bm * HW2 + pt * 64 + r) * 64 + cp * 16;
  *(s16x8*)(Qb + prow)     = *(const s16x8*)&T[r][cp * 16];
  *(s16x8*)(Qb + prow + 8) = *(const s16x8*)&T[r][cp * 16 + 8];
  *(s16x8*)(Kb + prow)     = *(const s16x8*)&T[r][64 + cp * 16];
  *(s16x8*)(Kb + prow + 8) = *(const s16x8*)&T[r][64 + cp * 16 + 8];
  size_t vrow = ((size_t)bm * 64 + r) * HW2 + pt * 64 + cp * 16;
  *(s16x8*)(Vt + vrow)     = *(const s16x8*)&T[r][128 + cp * 16];
  *(s16x8*)(Vt + vrow + 8) = *(const s16x8*)&T[r][128 + cp * 16 + 8];
}

// ---------------- fused attention ----------------
// wg = (bm, 16 q-rows). 4 waves; wave w owns columns [w*256, w*256+256).
// pos bias computed from the 15.9 KB table (L1-resident) instead of the 4 MB
// pe array: pe[i][j] = table[63*(j>>5 - i>>5) + (j&31 - i&31) + 1984], exact.
__global__ __launch_bounds__(256, 4) void k_attn(
    const unsigned short* __restrict__ Qb, const unsigned short* __restrict__ Kb,
    const unsigned short* __restrict__ Vt, const float* __restrict__ ptab,
    float* __restrict__ att, unsigned short* __restrict__ O) {
  int bm = blockIdx.x >> 6;
  int qt = blockIdx.x & 63;
  int wid = threadIdx.x >> 6, lane = threadIdx.x & 63;
  int l15 = lane & 15, lg = lane >> 4;

  __shared__ unsigned short P[16][1032];   // padded: row stride 2064 B
  __shared__ float redm[4][16];
  __shared__ float reds[4][16];
  __shared__ unsigned short Osm[16][68];   // O staging tile (padded)

  // Q A-frags (rows qt*16 .. +15)
  const unsigned short* qp = Qb + (size_t)(bm * HW2 + qt * 16 + l15) * 64 + lg * 8;
  s16x8 qa0 = *(const s16x8*)qp;
  s16x8 qa1 = *(const s16x8*)(qp + 32);

  // S = Q K^T over this wave's 256 columns
  f32x4 acc[16];
  const unsigned short* kbase = Kb + (size_t)bm * HW2 * 64;
  #pragma unroll
  for (int ct = 0; ct < 16; ++ct) {
    int col = wid * 256 + ct * 16 + l15;
    const unsigned short* kp = kbase + (size_t)col * 64 + lg * 8;
    s16x8 kb0 = *(const s16x8*)kp;
    s16x8 kb1 = *(const s16x8*)(kp + 32);
    f32x4 a = (f32x4){0.f, 0.f, 0.f, 0.f};
    a = mfma16(qa0, kb0, a);
    a = mfma16(qa1, kb1, a);
    acc[ct] = a;
  }

  // + pos bias from table, partial row max.
  // idx(qr, col) = 63*(col>>5) + (col&31) + 1984 - 63*(qr>>5) - (qr&31).
  // qr = qt*16 + lg*4 + i, so qr>>5 = qt>>1 (uniform) and qr&31 = (qt&1)*16+lg*4+i.
  int cbase = 1984 - 63 * (qt >> 1) - ((qt & 1) << 4) - lg * 4;
  float pmax[4] = {-1e30f, -1e30f, -1e30f, -1e30f};
  #pragma unroll
  for (int ct = 0; ct < 16; ++ct) {
    int col = wid * 256 + ct * 16 + l15;
    int t0 = 63 * (col >> 5) + (col & 31) + cbase;
    #pragma unroll
    for (int i = 0; i < 4; ++i) {
      float v = acc[ct][i] + ptab[t0 - i];
      acc[ct][i] = v;
      pmax[i] = fmaxf(pmax[i], v);
    }
  }
  #pragma unroll
  for (int i = 0; i < 4; ++i) {
    #pragma unroll
    for (int mk = 1; mk < 16; mk <<= 1)
      pmax[i] = fmaxf(pmax[i], __shfl_xor(pmax[i], mk));
  }
  if (l15 == 0) {
    #pragma unroll
    for (int i = 0; i < 4; ++i) redm[wid][lg * 4 + i] = pmax[i];
  }
  __syncthreads();
  float mrow[4];
  #pragma unroll
  for (int i = 0; i < 4; ++i) {
    int r = lg * 4 + i;
    mrow[i] = fmaxf(fmaxf(redm[0][r], redm[1][r]), fmaxf(redm[2][r], redm[3][r]));
  }

  // exp + partial sums
  float psum[4] = {0.f, 0.f, 0.f, 0.f};
  #pragma unroll
  for (int ct = 0; ct < 16; ++ct) {
    #pragma unroll
    for (int i = 0; i < 4; ++i) {
      float e = __expf(acc[ct][i] - mrow[i]);
      acc[ct][i] = e;
      psum[i] += e;
    }
  }
  #pragma unroll
  for (int i = 0; i < 4; ++i) {
    #pragma unroll
    for (int mk = 1; mk < 16; mk <<= 1) psum[i] += __shfl_xor(psum[i], mk);
  }
  if (l15 == 0) {
    #pragma unroll
    for (int i = 0; i < 4; ++i) reds[wid][lg * 4 + i] = psum[i];
  }
  __syncthreads();
  float inv[4];
  #pragma unroll
  for (int i = 0; i < 4; ++i) {
    int r = lg * 4 + i;
    inv[i] = 1.0f / (reds[0][r] + reds[1][r] + reds[2][r] + reds[3][r]);
  }

  // write att (f32) + P (bf16) to LDS
  float* abase = att + (size_t)(bm * HW2 + qt * 16) * HW2;
  #pragma unroll
  for (int ct = 0; ct < 16; ++ct) {
    int col = wid * 256 + ct * 16 + l15;
    #pragma unroll
    for (int i = 0; i < 4; ++i) {
      int rl = lg * 4 + i;
      float v = acc[ct][i] * inv[i];
      abase[(size_t)rl * HW2 + col] = v;
      P[rl][col] = f2b(v);
    }
  }
  __syncthreads();

  // o = P @ V  (wave wid -> dh tile wid*16)
  f32x4 o = (f32x4){0.f, 0.f, 0.f, 0.f};
  const unsigned short* vbase = Vt + (size_t)(bm * 64 + wid * 16 + l15) * HW2;
  #pragma unroll
  for (int kt = 0; kt < 32; ++kt) {
    s16x8 pa = *(const s16x8*)&P[l15][kt * 32 + lg * 8];
    s16x8 vb = *(const s16x8*)(vbase + kt * 32 + lg * 8);
    o = mfma16(pa, vb, o);
  }

  // O tile via LDS -> coalesced 8B stores (128B per 16 threads per row)
  #pragma unroll
  for (int i = 0; i < 4; ++i) Osm[lg * 4 + i][wid * 16 + l15] = f2b(o[i]);
  __syncthreads();
  int t = threadIdx.x;
  int row = t >> 4, cpo = t & 15;
  unsigned short* dst = O + (size_t)(bm * HW2 + qt * 16 + row) * 64 + cpo * 4;
  *(s16x4*)dst = *(const s16x4*)&Osm[row][cpo * 4];
}

// ---------------- head transform: out = gather(O) @ w_ht + b_ht ----------------
__global__ __launch_bounds__(256) void k_ht(
    const unsigned short* __restrict__ O, const unsigned short* __restrict__ WhtT,
    const float* __restrict__ b_ht, float* __restrict__ out) {
  int rt = blockIdx.x >> 1;
  int ch = blockIdx.x & 1;
  int wid = threadIdx.x >> 6, lane = threadIdx.x & 63;
  int wr = wid >> 1, wc = wid & 1;
  int l15 = lane & 15, lg = lane >> 4;
  int b = (rt * 32) >> 10;
  int p0 = (rt * 32) & 1023;

  __shared__ unsigned short A[32][520];   // padded: row stride 1040 B

  int t = threadIdx.x;
  #pragma unroll
  for (int j = 0; j < 8; ++j) {
    int idx = t * 8 + j * 2048;          // [0, 16384)
    int row = idx >> 9;
    int k0 = idx & 511;
    int m = k0 >> 6, kk = k0 & 63;
    const unsigned short* src = O + (size_t)((b * 8 + m) * HW2 + p0 + row) * 64 + kk;
    *(s16x8*)&A[row][k0] = *(const s16x8*)src;
  }
  __syncthreads();

  f32x4 acc[8];
  #pragma unroll
  for (int ct = 0; ct < 8; ++ct) acc[ct] = (f32x4){0.f, 0.f, 0.f, 0.f};

  #pragma unroll
  for (int kt = 0; kt < 16; ++kt) {
    s16x8 a = *(const s16x8*)&A[wr * 16 + l15][kt * 32 + lg * 8];
    #pragma unroll
    for (int ct = 0; ct < 8; ++ct) {
      int col = ch * 256 + wc * 128 + ct * 16 + l15;
      s16x8 bf = *(const s16x8*)(WhtT + (size_t)col * 512 + kt * 32 + lg * 8);
      acc[ct] = mfma16(a, bf, acc[ct]);
    }
  }

  #pragma unroll
  for (int ct = 0; ct < 8; ++ct) {
    int col = ch * 256 + wc * 128 + ct * 16 + l15;
    float bias = b_ht[col];
    #pragma unroll
    for (int i = 0; i < 4; ++i) {
      int rp = rt * 32 + wr * 16 + lg * 4 + i;
      out[(size_t)rp * 512 + col] = acc[ct][i] + bias;
    }
  }
}

// ---------------- launcher ----------------
extern "C" void kernel_launch(void* const* d_in, const int* in_sizes, int n_in,
                              void* d_out, int out_size, void* d_ws, size_t ws_size,
                              hipStream_t stream) {
  const float* x         = (const float*)d_in[0];
  const float* w_qkv     = (const float*)d_in[1];
  const float* b_qkv     = (const float*)d_in[2];
  const float* w_ht      = (const float*)d_in[3];
  const float* b_ht      = (const float*)d_in[4];
  const float* pos_table = (const float*)d_in[5];
  const int*   pos_idx   = (const int*)d_in[6];

  float* out = (float*)d_out;                  // 4,194,304
  float* att = out + 4194304;                  // 67,108,864
  float* pe  = att + 67108864;                 // 1,048,576

  char* ws = (char*)d_ws;
  unsigned short* Qb   = (unsigned short*)(ws);
  unsigned short* Kb   = (unsigned short*)(ws + (8u  << 20));
  unsigned short* Vt   = (unsigned short*)(ws + (16u << 20));
  unsigned short* O    = (unsigned short*)(ws + (24u << 20));
  unsigned short* Wtq  = (unsigned short*)(ws + (32u << 20));
  unsigned short* Wtk  = Wtq + 4096;
  unsigned short* Wtv  = Wtk + 4096;
  unsigned short* WhtT = (unsigned short*)(ws + (32u << 20) + 65536);

  k_prep<<<2064, 256, 0, stream>>>(w_qkv, w_ht, pos_table, pos_idx,
                                   Wtq, Wtk, Wtv, WhtT, pe);
  k_qkv <<<1024, 256, 0, stream>>>(x, b_qkv, Wtq, Wtk, Wtv, Qb, Kb, Vt);
  k_attn<<<4096, 256, 0, stream>>>(Qb, Kb, Vt, pos_table, att, O);
  k_ht  <<<512,  256, 0, stream>>>(O, WhtT, b_ht, out);
}